// Round 1
// baseline (361.649 us; speedup 1.0000x reference)
//
#include <hip/hip_runtime.h>
#include <math.h>

#define NN 588
#define EE 9408
#define HD 64
#define NBLK 32
#define NTHR 256
#define GSZ (NBLK*NTHR)
#define NEGS 0.01f
#define THRESHV 0.999f
#define MAGIC 0x51CAFE17u

struct Ws {
  unsigned ready, cnt, gen, stop;
  int deg[NN];
  int off[NN+1];
  int cursor[NN];
  int eidx[EE];
  float xbuf0[NN*HD];
  float xbuf1[NN*HD];
  float ybuf[NN];
  float gx[192];
};

__device__ __forceinline__ float lrelu(float v){ return v >= 0.f ? v : NEGS*v; }
__device__ __forceinline__ float sigm(float v){ return 1.f/(1.f+expf(-v)); }

// Grid barrier: sense-reversal via generation counter, agent scope.
__device__ __forceinline__ void gbar(Ws* w) {
  __syncthreads();
  if (threadIdx.x == 0) {
    __threadfence();  // release: flush this CU/XCD writes to coherent point
    unsigned g = __hip_atomic_load(&w->gen, __ATOMIC_RELAXED, __HIP_MEMORY_SCOPE_AGENT);
    unsigned a = __hip_atomic_fetch_add(&w->cnt, 1u, __ATOMIC_ACQ_REL, __HIP_MEMORY_SCOPE_AGENT);
    if (a == (unsigned)(NBLK-1)) {
      __hip_atomic_store(&w->cnt, 0u, __ATOMIC_RELAXED, __HIP_MEMORY_SCOPE_AGENT);
      __hip_atomic_store(&w->gen, g+1u, __ATOMIC_RELEASE, __HIP_MEMORY_SCOPE_AGENT);
    } else {
      long bail = 0;
      while (__hip_atomic_load(&w->gen, __ATOMIC_ACQUIRE, __HIP_MEMORY_SCOPE_AGENT) == g) {
        __builtin_amdgcn_s_sleep(1);
        if (++bail > (1L<<26)) break;  // safety valve: never hard-hang
      }
    }
    __threadfence();  // acquire: invalidate caches so fresh data is read
    }
  __syncthreads();
}

// gx[j] = bi[j] + sum_n inp[n]*wi[j*NN+n]; inp recomputed per block in LDS
// (inp[n] = lrelu(b3 + sum_{e: dst==n} ybuf[src_e])). Rows split across blocks.
__device__ void phase_gx(Ws* w, const float* wi, const float* bi, float b3v,
                         float* sInp, float* sRed, int bid, int tid) {
  for (int n = tid; n < NN; n += NTHR) {
    float a = 0.f;
    int e0 = w->off[n], e1 = w->off[n+1];
    for (int k = e0; k < e1; ++k) a += w->ybuf[w->eidx[k]];
    sInp[n] = lrelu(a + b3v);
  }
  __syncthreads();
  const int RPB = 192/NBLK;  // 6 rows per block
  for (int rr = 0; rr < RPB; ++rr) {
    int j = bid*RPB + rr;
    const float* row = wi + j*NN;
    float p = 0.f;
    for (int n = tid; n < NN; n += NTHR) p += sInp[n]*row[n];
    sRed[tid] = p;
    __syncthreads();
    if (tid < 128) sRed[tid] += sRed[tid+128];
    __syncthreads();
    if (tid < 64) {
      float v = sRed[tid] + sRed[tid+64];
      for (int o = 32; o; o >>= 1) v += __shfl_down(v, o, 64);
      if (tid == 0) w->gx[j] = v + bi[j];
    }
    __syncthreads();
  }
}

__global__ __launch_bounds__(NTHR)
void lastgcn_kernel(const float* feat, const int* src, const int* dst,
                    const float* W1, const float* b1, const float* W2, const float* b2,
                    const float* W3, const float* b3, const float* W5, const float* b5,
                    const float* wi, const float* wh, const float* bi, const float* bh,
                    const float* w_end, const float* b_end, const int* capp,
                    float* out, Ws* w) {
  const int tid = threadIdx.x;
  const int bid = blockIdx.x;
  const int gtid = bid*NTHR + tid;

  __shared__ float sInp[NN];
  __shared__ float sRed[NTHR];
  __shared__ float sPart[4*HD];
  __shared__ float sAgg[HD];
  __shared__ float sMM[4*HD];
  __shared__ float sState[HD];   // block 0 only
  __shared__ float sGh[192];     // block 0 only
  __shared__ float sScal[4];     // block 0: s, fprob, counter
  __shared__ int   sScan[NTHR];
  __shared__ unsigned sStop;

  // ---- init gate: block 0 zeroes deg + control words, then releases others ----
  if (bid == 0) {
    for (int n = tid; n < NN; n += NTHR) w->deg[n] = 0;
    __syncthreads();
    if (tid == 0) {
      __hip_atomic_store(&w->cnt, 0u, __ATOMIC_RELAXED, __HIP_MEMORY_SCOPE_AGENT);
      __hip_atomic_store(&w->gen, 0u, __ATOMIC_RELAXED, __HIP_MEMORY_SCOPE_AGENT);
      __hip_atomic_store(&w->stop, 0u, __ATOMIC_RELAXED, __HIP_MEMORY_SCOPE_AGENT);
      __threadfence();
      __hip_atomic_store(&w->ready, MAGIC, __ATOMIC_RELEASE, __HIP_MEMORY_SCOPE_AGENT);
    }
  } else if (tid == 0) {
    long bail = 0;
    while (__hip_atomic_load(&w->ready, __ATOMIC_ACQUIRE, __HIP_MEMORY_SCOPE_AGENT) != MAGIC) {
      __builtin_amdgcn_s_sleep(1);
      if (++bail > (1L<<26)) break;
    }
    __threadfence();
  }
  __syncthreads();

  // ---- P1: degree count ----
  for (int e = gtid; e < EE; e += GSZ) atomicAdd(&w->deg[dst[e]], 1);
  gbar(w);

  // ---- P2: exclusive prefix (block 0) ----
  if (bid == 0) {
    const int CH = (NN + NTHR - 1)/NTHR;  // 3
    int c[3]; int mysum = 0;
    for (int i = 0; i < CH; ++i) { int n = tid*CH+i; c[i] = (n < NN) ? w->deg[n] : 0; mysum += c[i]; }
    sScan[tid] = mysum;
    __syncthreads();
    for (int o = 1; o < NTHR; o <<= 1) {
      int v = (tid >= o) ? sScan[tid-o] : 0;
      __syncthreads();
      sScan[tid] += v;
      __syncthreads();
    }
    int run = sScan[tid] - mysum;
    for (int i = 0; i < CH; ++i) {
      int n = tid*CH+i;
      if (n < NN) { w->off[n] = run; w->cursor[n] = run; run += c[i]; }
    }
    if (tid == NTHR-1) w->off[NN] = sScan[NTHR-1];
  }
  gbar(w);

  // ---- P3: scatter src indices by dst ----
  for (int e = gtid; e < EE; e += GSZ) {
    int p = atomicAdd(&w->cursor[dst[e]], 1);
    w->eidx[p] = src[e];
  }
  gbar(w);

  // ---- P4: x = lrelu(conv(features,W1,b1)); y0[n] = dot(x[n],W3) ----
  for (int n = gtid; n < NN; n += GSZ) {
    float f0=0.f,f1=0.f,f2=0.f,f3=0.f;
    int e0 = w->off[n], e1 = w->off[n+1];
    for (int k = e0; k < e1; ++k) {
      const float* fp = feat + w->eidx[k]*4;
      f0 += fp[0]; f1 += fp[1]; f2 += fp[2]; f3 += fp[3];
    }
    float yacc = 0.f;
    for (int j = 0; j < HD; ++j) {
      float v = b1[j] + f0*W1[j] + f1*W1[HD+j] + f2*W1[2*HD+j] + f3*W1[3*HD+j];
      v = lrelu(v);
      w->xbuf0[n*HD+j] = v;
      yacc += v * W3[j];
    }
    w->ybuf[n] = yacc;
  }
  gbar(w);

  // ---- P5: initial gx (distributed) ----
  phase_gx(w, wi, bi, b3[0], sInp, sRed, bid, tid);
  gbar(w);

  // ---- P6: GRU init tail (block 0): state, gh_state, fprob0, s0 ----
  if (bid == 0) {
    if (tid < 64) {
      int j = tid;
      float r  = sigm(w->gx[j]     + bh[j]);
      float z  = sigm(w->gx[64+j]  + bh[64+j]);
      float nn = tanhf(w->gx[128+j] + r*bh[128+j]);
      sState[j] = (1.f - z)*nn;   // h0 = 0
    }
    __syncthreads();
    for (int j = tid; j < 192; j += NTHR) {
      float a = bh[j];
      const float* whr = wh + j*64;
      for (int k = 0; k < 64; ++k) a += sState[k]*whr[k];
      sGh[j] = a;
    }
    if (tid < 64) {
      float v = sState[tid]*w_end[tid];
      for (int o = 32; o; o >>= 1) v += __shfl_down(v, o, 64);
      if (tid == 0) {
        float pr = sigm(v + b_end[0]);
        sScal[0] = pr;   // s
        sScal[1] = pr;   // fprob
        sScal[2] = 0.f;  // counter
        __hip_atomic_store(&w->stop, (pr >= THRESHV) ? 1u : 0u,
                           __ATOMIC_RELAXED, __HIP_MEMORY_SCOPE_AGENT);
      }
    }
  }
  gbar(w);

  // ---- main loop ----
  const int cap = capp[0];
  int curIdx = 0;
  float* bufs0 = w->xbuf0;
  float* bufs1 = w->xbuf1;
  for (int it = 0; it < cap; ++it) {
    if (tid == 0) sStop = __hip_atomic_load(&w->stop, __ATOMIC_RELAXED, __HIP_MEMORY_SCOPE_AGENT);
    __syncthreads();
    if (sStop) break;   // uniform across all blocks

    const float* xc = curIdx ? bufs1 : bufs0;
    float*       xn = curIdx ? bufs0 : bufs1;

    // Pa: xn = lrelu(conv(xc,W2,b2)); y[n] = dot(xn[n],W3). Block-owned nodes.
    const int nb = (NN + NBLK - 1)/NBLK;  // 19
    int nbeg = bid*nb;
    int nend = nbeg + nb; if (nend > NN) nend = NN;
    int dim = tid & 63, part = tid >> 6;
    for (int n = nbeg; n < nend; ++n) {
      int e0 = w->off[n], e1 = w->off[n+1];
      float acc = 0.f;
      for (int k = e0 + part; k < e1; k += 4)
        acc += xc[w->eidx[k]*HD + dim];
      sPart[part*HD + dim] = acc;
      __syncthreads();
      if (tid < HD) sAgg[tid] = sPart[tid] + sPart[HD+tid] + sPart[2*HD+tid] + sPart[3*HD+tid];
      __syncthreads();
      {
        const float* w2c = W2 + dim;
        float p = 0.f;
        #pragma unroll
        for (int k = part*16; k < part*16 + 16; ++k) p += sAgg[k]*w2c[k*HD];
        sMM[part*HD + dim] = p;
      }
      __syncthreads();
      if (tid < HD) {
        int j = tid;
        float v = b2[j] + sMM[j] + sMM[HD+j] + sMM[2*HD+j] + sMM[3*HD+j];
        v = lrelu(v);
        xn[n*HD + j] = v;
        float yv = v * W3[j];
        for (int o = 32; o; o >>= 1) yv += __shfl_down(yv, o, 64);
        if (j == 0) w->ybuf[n] = yv;
      }
      __syncthreads();
    }
    gbar(w);

    // Pb: gx (distributed; each block rebuilds inp locally)
    phase_gx(w, wi, bi, b3[0], sInp, sRed, bid, tid);
    gbar(w);

    // Pc: GRU tail + scalar updates (block 0)
    if (bid == 0) {
      if (tid < 64) {
        int j = tid;
        float r  = sigm(w->gx[j]      + sGh[j]);
        float z  = sigm(w->gx[64+j]   + sGh[64+j]);
        float nn = tanhf(w->gx[128+j] + r*sGh[128+j]);
        float st = (1.f - z)*nn + z*sState[j];
        float v = st * w_end[j];
        for (int o = 32; o; o >>= 1) v += __shfl_down(v, o, 64);
        if (j == 0) {
          float pr = sigm(v + b_end[0]);
          sScal[0] += pr;      // s += sum(pr)
          sScal[1]  = pr;      // fprob = pr
          sScal[2] += 1.f;     // counter++
          __hip_atomic_store(&w->stop, (sScal[0] >= THRESHV) ? 1u : 0u,
                             __ATOMIC_RELAXED, __HIP_MEMORY_SCOPE_AGENT);
        }
      }
    }
    gbar(w);
    curIdx ^= 1;
  }

  // ---- final: out = conv(x_last, W5, b5) ----
  {
    const float* xc = curIdx ? bufs1 : bufs0;
    const int nb = (NN + NBLK - 1)/NBLK;
    int nbeg = bid*nb;
    int nend = nbeg + nb; if (nend > NN) nend = NN;
    int dim = tid & 63, part = tid >> 6;
    for (int n = nbeg; n < nend; ++n) {
      int e0 = w->off[n], e1 = w->off[n+1];
      float acc = 0.f;
      for (int k = e0 + part; k < e1; k += 4)
        acc += xc[w->eidx[k]*HD + dim];
      sPart[part*HD + dim] = acc;
      __syncthreads();
      if (tid < HD) sAgg[tid] = sPart[tid] + sPart[HD+tid] + sPart[2*HD+tid] + sPart[3*HD+tid];
      __syncthreads();
      if (tid < 3) {
        float v = b5[tid];
        for (int k = 0; k < HD; ++k) v += sAgg[k]*W5[k*3+tid];
        out[n*3 + tid] = v;
      }
      __syncthreads();
    }
    if (bid == 0 && tid == 0) {
      out[NN*3]     = sScal[2];  // counter (as float)
      out[NN*3 + 1] = sScal[1];  // fprob
    }
  }
}

extern "C" void kernel_launch(void* const* d_in, const int* in_sizes, int n_in,
                              void* d_out, int out_size, void* d_ws, size_t ws_size,
                              hipStream_t stream) {
  const float* feat  = (const float*)d_in[0];
  const int*   src   = (const int*)d_in[1];
  const int*   dst   = (const int*)d_in[2];
  const float* W1    = (const float*)d_in[3];
  const float* b1    = (const float*)d_in[4];
  const float* W2    = (const float*)d_in[5];
  const float* b2    = (const float*)d_in[6];
  const float* W3    = (const float*)d_in[7];
  const float* b3    = (const float*)d_in[8];
  const float* W5    = (const float*)d_in[9];
  const float* b5    = (const float*)d_in[10];
  const float* wi    = (const float*)d_in[11];
  const float* wh    = (const float*)d_in[12];
  const float* bi    = (const float*)d_in[13];
  const float* bh    = (const float*)d_in[14];
  const float* w_end = (const float*)d_in[15];
  const float* b_end = (const float*)d_in[16];
  const int*   capp  = (const int*)d_in[17];

  float* out = (float*)d_out;
  Ws* w = (Ws*)d_ws;

  lastgcn_kernel<<<dim3(NBLK), dim3(NTHR), 0, stream>>>(
      feat, src, dst, W1, b1, W2, b2, W3, b3, W5, b5,
      wi, wh, bi, bh, w_end, b_end, capp, out, w);
}